// Round 3
// baseline (121.610 us; speedup 1.0000x reference)
//
#include <hip/hip_runtime.h>
#include <hip/hip_bf16.h>

typedef __bf16 bf16x8 __attribute__((ext_vector_type(8)));
typedef unsigned short u16x8 __attribute__((ext_vector_type(8)));
typedef unsigned int u32x2 __attribute__((ext_vector_type(2)));
typedef unsigned int u32x4 __attribute__((ext_vector_type(4)));
typedef float f32x4 __attribute__((ext_vector_type(4)));
typedef unsigned short u16;

constexpr int DIMc = 256, Tt = 2048, Dd = 64;

__device__ __forceinline__ u16 f2b(float f) {   // RNE float->bf16 bits
  unsigned u = __float_as_uint(f);
  return (u16)((u + 0x7FFFu + ((u >> 16) & 1u)) >> 16);
}
__device__ __forceinline__ float b2f(u16 v) {
  return __uint_as_float(((unsigned)v) << 16);
}
__device__ __forceinline__ unsigned f2b2(float a, float b) {  // packed RNE pair (low=a)
  return (unsigned)f2b(a) | ((unsigned)f2b(b) << 16);
}
__device__ __forceinline__ f32x4 mfma16(u16x8 a, u16x8 b, f32x4 c) {
  return __builtin_amdgcn_mfma_f32_16x16x32_bf16(
      __builtin_bit_cast(bf16x8, a), __builtin_bit_cast(bf16x8, b), c, 0, 0, 0);
}

// Fused NSVQ, 2 blocks/CU. Block = 64 tokens, 256 threads (4 waves), grid 512.
// LDS (u16 offsets): WinT[64][288] @0 (WoX[256][72] aliases it after encode, both
// 36864 B) ; InT[64][256] @18432 ; Xt[64][64] @34816 ; mnp[4][64]f @38912.
// Total 78,848 B -> 2 resident blocks/CU (157,696 <= 160 KiB). 3 barriers.
// -2x folded into codebook side: bf16(-2c) == -2*bf16(c) exactly, so distance
// products are bit-identical to the (-2x)*c scheme; saves the whole Xm buffer.
__global__ __launch_bounds__(256, 2) void nsvq_fused(
    const float* __restrict__ in, const float* __restrict__ rnd,
    const float* __restrict__ cb, const float* __restrict__ Win,
    const float* __restrict__ bin, const float* __restrict__ Wout,
    const float* __restrict__ bout, float* __restrict__ out) {
  __shared__ u16 sm[39424];
  u16* const WinT = sm;                     // [64][288] bf16 (encode A-tiles)
  u16* const WoX  = sm;                     // [256][72] bf16 (decode A-tiles, aliased)
  u16* const InT  = sm + 18432;             // [64][256] bf16, 16B-block XOR swizzle
  u16* const Xt   = sm + 34816;             // [64][64] bf16 x (later q), swizzled
  float* const mnp = (float*)(sm + 38912);  // [4][64] per-wave code-slice mins

  const int tid  = threadIdx.x;
  const int lane = tid & 63;
  const int w    = tid >> 6;                // 0..3
  const int quad = lane >> 4, col = lane & 15;
  const int b    = blockIdx.x >> 5;         // 16 batches x 32 token-tiles
  const int t0   = (blockIdx.x & 31) << 6;
  const int myt  = w * 16 + col;            // own token row in block (0..63)

  // ---- stage WinT: Win[c][d] -> WinT[d][c] bf16 (lanes = consecutive c) ----
  {
    const int c = tid;                      // 0..255
    #pragma unroll
    for (int k = 0; k < 8; ++k) {
      const int d0 = k * 8;
      const float4* wr = (const float4*)(Win + c * 64 + d0);
      float4 v0 = wr[0], v1 = wr[1];
      u16* dst = WinT + c;
      dst[(d0 + 0) * 288] = f2b(v0.x); dst[(d0 + 1) * 288] = f2b(v0.y);
      dst[(d0 + 2) * 288] = f2b(v0.z); dst[(d0 + 3) * 288] = f2b(v0.w);
      dst[(d0 + 4) * 288] = f2b(v1.x); dst[(d0 + 5) * 288] = f2b(v1.y);
      dst[(d0 + 6) * 288] = f2b(v1.z); dst[(d0 + 7) * 288] = f2b(v1.w);
    }
  }
  // ---- stage InT (fp32 -> bf16, transpose, packed 16B swizzled writes) ----
  {
    const int t = tid & 63, cg = tid >> 6;
    const float* ib = in + (size_t)b * DIMc * Tt + t0 + t;
    #pragma unroll
    for (int it = 0; it < 8; ++it) {
      const int c0 = cg * 8 + it * 32;
      u32x4 pk;
      #pragma unroll
      for (int jj = 0; jj < 4; ++jj)
        pk[jj] = f2b2(ib[(size_t)(c0 + 2 * jj) * Tt], ib[(size_t)(c0 + 2 * jj + 1) * Tt]);
      *(u32x4*)(InT + t * 256 + (((c0 >> 3) ^ (t & 7)) << 3)) = pk;
    }
  }
  // ---- rr2 of own token; cache rnd in regs for the q-update (reads rnd once) ----
  float rr2v = 0.f, rv[16];
  const float* rb = rnd + ((size_t)b * Tt + t0) * Dd;
  #pragma unroll
  for (int tt = 0; tt < 16; ++tt) {
    rv[tt] = rb[(size_t)(w * 16 + tt) * Dd + lane];
    float s = rv[tt] * rv[tt];
    s += __shfl_xor(s, 1);  s += __shfl_xor(s, 2);  s += __shfl_xor(s, 4);
    s += __shfl_xor(s, 8);  s += __shfl_xor(s, 16); s += __shfl_xor(s, 32);
    if (col == tt) rr2v = s;
  }
  __syncthreads();   // InT + WinT ready

  // ---- encode: X^T = WinT · InT, acc init = bin (f32-exact bias) ----
  f32x4 acc[4];
  {
    u16x8 Bf[8];
    #pragma unroll
    for (int kt = 0; kt < 8; ++kt)
      Bf[kt] = *(const u16x8*)(InT + myt * 256 + (((kt * 4 + quad) ^ (myt & 7)) << 3));
    #pragma unroll
    for (int mt = 0; mt < 4; ++mt) {
      float4 bi = *(const float4*)(bin + mt * 16 + quad * 4);
      f32x4 a = {bi.x, bi.y, bi.z, bi.w};
      #pragma unroll
      for (int kt = 0; kt < 8; ++kt) {
        u16x8 A = *(const u16x8*)(WinT + (mt * 16 + col) * 288 + kt * 32 + quad * 8);
        a = mfma16(A, Bf[kt], a);
      }
      acc[mt] = a;
    }
  }
  float x2v = 0.f;
  #pragma unroll
  for (int mt = 0; mt < 4; ++mt) {
    #pragma unroll
    for (int r = 0; r < 4; ++r) x2v = fmaf(acc[mt][r], acc[mt][r], x2v);
    u32x2 px = { f2b2(acc[mt][0], acc[mt][1]), f2b2(acc[mt][2], acc[mt][3]) };
    const int bk  = mt * 2 + (quad >> 1);
    const int off = myt * 64 + ((bk ^ (myt & 7)) << 3) + (quad & 1) * 4;
    *(u32x2*)(Xt + off) = px;
  }
  x2v += __shfl_xor(x2v, 16);
  x2v += __shfl_xor(x2v, 32);
  __syncthreads();   // Xt complete (cross-wave reads next); WinT dead -> WoX aliases

  // ---- stage WoX: Wout[d][c] -> WoX[c][d] (coalesced reads, b128 writes) ----
  {
    const int c = tid;                      // 0..255
    #pragma unroll
    for (int k = 0; k < 8; ++k) {
      const int d0 = k * 8;
      u32x4 pk;
      #pragma unroll
      for (int jj = 0; jj < 4; ++jj)
        pk[jj] = f2b2(Wout[(size_t)(d0 + 2 * jj) * 256 + c],
                      Wout[(size_t)(d0 + 2 * jj + 1) * 256 + c]);
      *(u32x4*)(WoX + c * 72 + d0) = pk;
    }
  }
  // ---- distances: wave-private 256-code slice, cb global->regs, A = bf16(-2c);
  //      acc init = c^2 (f32-exact) ----
  u16x8 Xa[4], Xb[4];
  #pragma unroll
  for (int nt = 0; nt < 4; ++nt) {
    const int tr = nt * 16 + col;
    Xa[nt] = *(const u16x8*)(Xt + tr * 64 + ((quad ^ (tr & 7)) << 3));
    Xb[nt] = *(const u16x8*)(Xt + tr * 64 + (((4 + quad) ^ (tr & 7)) << 3));
  }
  float minv[4];
  #pragma unroll
  for (int i = 0; i < 4; ++i) minv[i] = 3.4e38f;
  const float* cw = cb + (size_t)(w * 256) * Dd;
  for (int mi = 0; mi < 16; ++mi) {
    const float* cr = cw + (size_t)(mi * 16 + col) * Dd + quad * 8;
    float4 c0 = ((const float4*)cr)[0],        c1 = ((const float4*)cr)[1];
    float4 c2 = ((const float4*)(cr + 32))[0], c3 = ((const float4*)(cr + 32))[1];
    float cnA = fmaf(c0.w, c0.w, fmaf(c0.z, c0.z, fmaf(c0.y, c0.y, c0.x * c0.x)));
    float cnB = fmaf(c1.w, c1.w, fmaf(c1.z, c1.z, fmaf(c1.y, c1.y, c1.x * c1.x)));
    float cnC = fmaf(c2.w, c2.w, fmaf(c2.z, c2.z, fmaf(c2.y, c2.y, c2.x * c2.x)));
    float cnD = fmaf(c3.w, c3.w, fmaf(c3.z, c3.z, fmaf(c3.y, c3.y, c3.x * c3.x)));
    float cn = (cnA + cnB) + (cnC + cnD);
    cn += __shfl_xor(cn, 16); cn += __shfl_xor(cn, 32);   // full ||c||^2
    f32x4 cn4;
    #pragma unroll
    for (int r = 0; r < 4; ++r) cn4[r] = __shfl(cn, quad * 4 + r);
    u32x4 a0 = { f2b2(-2.f * c0.x, -2.f * c0.y), f2b2(-2.f * c0.z, -2.f * c0.w),
                 f2b2(-2.f * c1.x, -2.f * c1.y), f2b2(-2.f * c1.z, -2.f * c1.w) };
    u32x4 a1 = { f2b2(-2.f * c2.x, -2.f * c2.y), f2b2(-2.f * c2.z, -2.f * c2.w),
                 f2b2(-2.f * c3.x, -2.f * c3.y), f2b2(-2.f * c3.z, -2.f * c3.w) };
    u16x8 A0 = __builtin_bit_cast(u16x8, a0);
    u16x8 A1 = __builtin_bit_cast(u16x8, a1);
    #pragma unroll
    for (int nt = 0; nt < 4; ++nt) {
      f32x4 a = mfma16(A0, Xa[nt], cn4);    // c^2 + x·(-2c)
      a = mfma16(A1, Xb[nt], a);
      #pragma unroll
      for (int r = 0; r < 4; ++r) minv[nt] = fminf(minv[nt], a[r]);
    }
  }
  #pragma unroll
  for (int nt = 0; nt < 4; ++nt) {
    float m = minv[nt];
    m = fminf(m, __shfl_xor(m, 16));
    m = fminf(m, __shfl_xor(m, 32));
    mnp[w * 64 + nt * 16 + col] = m;        // all quads write same value
  }
  __syncthreads();   // mnp + WoX ready

  // ---- q = x + sc*rnd (own token rows; lane = d; rnd from reg cache) ----
  float mv = 3.4e38f;
  #pragma unroll
  for (int j = 0; j < 4; ++j) mv = fminf(mv, mnp[j * 64 + myt]);
  float r2  = fmaxf(x2v + mv, 0.f);                 // ||x - hard||^2
  float scv = sqrtf(r2) / (sqrtf(rr2v) + 1e-12f);
  #pragma unroll
  for (int tt = 0; tt < 16; ++tt) {
    float s  = __shfl(scv, tt);
    const int tr  = w * 16 + tt;
    const int idx = tr * 64 + (((lane >> 3) ^ (tr & 7)) << 3) + (lane & 7);
    Xt[idx] = f2b(fmaf(s, rv[tt], b2f(Xt[idx])));
  }

  // ---- decode: out = WoX · q, acc init = bout (f32-exact bias) ----
  u16x8 Q0 = *(const u16x8*)(Xt + myt * 64 + ((quad ^ (myt & 7)) << 3));
  u16x8 Q1 = *(const u16x8*)(Xt + myt * 64 + (((4 + quad) ^ (myt & 7)) << 3));
  float* ob0 = out + (size_t)b * DIMc * Tt + t0 + myt;
  #pragma unroll
  for (int mt = 0; mt < 16; ++mt) {
    const u16* ar = WoX + (mt * 16 + col) * 72;
    u16x8 A0 = *(const u16x8*)(ar + quad * 8);
    u16x8 A1 = *(const u16x8*)(ar + 32 + quad * 8);
    float4 bo = *(const float4*)(bout + mt * 16 + quad * 4);
    f32x4 a = {bo.x, bo.y, bo.z, bo.w};
    a = mfma16(A0, Q0, a);
    a = mfma16(A1, Q1, a);
    float* ob = ob0 + (size_t)(mt * 16 + quad * 4) * Tt;
    #pragma unroll
    for (int r = 0; r < 4; ++r) ob[(size_t)r * Tt] = a[r];
  }
}

extern "C" void kernel_launch(void* const* d_in, const int* in_sizes, int n_in,
                              void* d_out, int out_size, void* d_ws, size_t ws_size,
                              hipStream_t stream) {
  const float *in = nullptr, *cbp = nullptr, *rnd = nullptr, *bin = nullptr, *bout = nullptr;
  const float* w16[2] = {nullptr, nullptr}; int nw = 0;
  for (int i = 0; i < n_in; ++i) {
    switch (in_sizes[i]) {
      case 8388608: in  = (const float*)d_in[i]; break;
      case 65536:   cbp = (const float*)d_in[i]; break;
      case 2097152: rnd = (const float*)d_in[i]; break;
      case 64:      bin = (const float*)d_in[i]; break;
      case 256:     bout= (const float*)d_in[i]; break;
      case 16384:   if (nw < 2) w16[nw++] = (const float*)d_in[i]; break;
      default: break;
    }
  }
  if (!in)   in  = (const float*)d_in[0];
  if (!cbp)  cbp = (const float*)d_in[1];
  if (nw < 2) { w16[0] = (const float*)d_in[2]; w16[1] = (const float*)d_in[4]; }
  if (!bin)  bin = (const float*)d_in[3];
  if (!bout) bout = (const float*)d_in[5];
  if (!rnd)  rnd = (const float*)d_in[6];

  nsvq_fused<<<512, 256, 0, stream>>>(in, rnd, cbp, w16[0], bin, w16[1], bout, (float*)d_out);
}

// Round 4
// 115.804 us; speedup vs baseline: 1.0501x; 1.0501x over previous
//
#include <hip/hip_runtime.h>
#include <hip/hip_bf16.h>

typedef __bf16 bf16x8 __attribute__((ext_vector_type(8)));
typedef unsigned short u16x8 __attribute__((ext_vector_type(8)));
typedef unsigned int u32x2 __attribute__((ext_vector_type(2)));
typedef float f32x4 __attribute__((ext_vector_type(4)));
typedef unsigned short u16;

constexpr int DIMc = 256, Tt = 2048, Dd = 64;

// ws layout (u16 units):
//   CbF[1024][64] @0       : bf16(-2*c), fragment-row order (code-major) = 128 KB
//   CN[1024] f32  @65536   : ||c||^2 (exact partial-sum tree)            =   4 KB
//   WinT image    @67584   : [64][256] bf16, XOR-swizzled LDS image      =  32 KB
//   WoX  image    @83968   : [256][64] bf16, XOR-swizzled LDS image      =  32 KB
#define CBF_U  0
#define CN_U   65536
#define WINT_U 67584
#define WOX_U  83968

__device__ __forceinline__ u16 f2b(float f) {   // RNE float->bf16 bits
  unsigned u = __float_as_uint(f);
  return (u16)((u + 0x7FFFu + ((u >> 16) & 1u)) >> 16);
}
__device__ __forceinline__ float b2f(u16 v) {
  return __uint_as_float(((unsigned)v) << 16);
}
__device__ __forceinline__ unsigned f2b2(float a, float b) {  // packed RNE pair (low=a)
  return (unsigned)f2b(a) | ((unsigned)f2b(b) << 16);
}
__device__ __forceinline__ f32x4 mfma16(u16x8 a, u16x8 b, f32x4 c) {
  return __builtin_amdgcn_mfma_f32_16x16x32_bf16(
      __builtin_bit_cast(bf16x8, a), __builtin_bit_cast(bf16x8, b), c, 0, 0, 0);
}
// async 16B/lane global->LDS DMA; LDS dst = uniform base + lane*16 (HW rule)
__device__ __forceinline__ void dma16(const u16* g, u16* l) {
  __builtin_amdgcn_global_load_lds(
      (const __attribute__((address_space(1))) unsigned int*)g,
      (__attribute__((address_space(3))) unsigned int*)l, 16, 0, 0);
}

// Prep: all fp32->bf16 weight conversion + transposition done ONCE (not per block).
__global__ void nsvq_prep(const float* __restrict__ cb, const float* __restrict__ Win,
                          const float* __restrict__ Wout, u16* __restrict__ wsu) {
  const int g = blockIdx.x * 256 + threadIdx.x;   // 64 blocks -> 16384 threads
  {  // CbF: 4 values/thread, value = bf16(-2c); row k is MFMA-A fragment-ready
    const int k = g >> 4, j = (g & 15) << 2;
    float4 v = *(const float4*)(cb + k * 64 + j);
    u16* row = wsu + CBF_U + k * 64 + j;
    row[0] = f2b(-2.f * v.x); row[1] = f2b(-2.f * v.y);
    row[2] = f2b(-2.f * v.z); row[3] = f2b(-2.f * v.w);
  }
  if (g < 1024) {  // CN: exact same partial-sum tree as the old in-kernel version
    const float* cr = cb + g * 64;
    float p[4];
    #pragma unroll
    for (int q = 0; q < 4; ++q) {
      float4 a0 = ((const float4*)(cr + q * 8))[0],      a1 = ((const float4*)(cr + q * 8))[1];
      float4 a2 = ((const float4*)(cr + 32 + q * 8))[0], a3 = ((const float4*)(cr + 32 + q * 8))[1];
      float pA = fmaf(a0.w, a0.w, fmaf(a0.z, a0.z, fmaf(a0.y, a0.y, a0.x * a0.x)));
      float pB = fmaf(a1.w, a1.w, fmaf(a1.z, a1.z, fmaf(a1.y, a1.y, a1.x * a1.x)));
      float pC = fmaf(a2.w, a2.w, fmaf(a2.z, a2.z, fmaf(a2.y, a2.y, a2.x * a2.x)));
      float pD = fmaf(a3.w, a3.w, fmaf(a3.z, a3.z, fmaf(a3.y, a3.y, a3.x * a3.x)));
      p[q] = (pA + pB) + (pC + pD);
    }
    ((float*)(wsu + CN_U))[g] = (p[0] + p[1]) + (p[2] + p[3]);
  }
  {  // WinT image: [d][c] swizzled (exact LDS image for DMA)
    const int d = g >> 8, c = g & 255;
    wsu[WINT_U + d * 256 + (((c >> 3) ^ (d & 7)) << 3) + (c & 7)] = f2b(Win[c * 64 + d]);
  }
  {  // WoX image: [c][d] swizzled (exact LDS image for DMA)
    const int c = g >> 6, d = g & 63;
    wsu[WOX_U + c * 64 + (((d >> 3) ^ (c & 7)) << 3) + (d & 7)] = f2b(Wout[d * 256 + c]);
  }
}

// Main: block = 64 tokens, 256 threads (4 waves), grid 512.
// LDS (u16): WinT[64][256] swz @0 (WoX[256][64] swz aliases it) ; Xt[64][64] swz
// @16384 ; mnp[4][64]f @20480. Total 41,984 B -> 3 blocks/CU LDS cap. 3 barriers.
__global__ __launch_bounds__(256, 3) void nsvq_main(
    const float* __restrict__ in, const float* __restrict__ rnd,
    const float* __restrict__ bin, const float* __restrict__ bout,
    const u16* __restrict__ wsu, float* __restrict__ out) {
  __shared__ u16 sm[20992];
  u16* const WinT = sm;                     // [64][256] bf16 swz (encode A)
  u16* const WoX  = sm;                     // [256][64] bf16 swz (decode A, aliased)
  u16* const Xt   = sm + 16384;             // [64][64] bf16 x (later q), swz
  float* const mnp = (float*)(sm + 20480);  // [4][64] per-wave code-slice mins

  const int tid  = threadIdx.x;
  const int lane = tid & 63;
  const int w    = tid >> 6;                // 0..3
  const int quad = lane >> 4, col = lane & 15;
  const int b    = blockIdx.x >> 5;         // 16 batches x 32 token-tiles
  const int t0   = (blockIdx.x & 31) << 6;
  const int myt  = w * 16 + col;            // own token row in block (0..63)

  // ---- WinT DMA (32 KB = 32 instrs, 8 per wave), fully async ----
  #pragma unroll
  for (int ii = 0; ii < 8; ++ii) {
    const int i = w + 4 * ii;
    dma16(wsu + WINT_U + i * 512 + lane * 8, WinT + i * 512);
  }
  // ---- encode B-fragments straight from global (own token only; 64B-granule) ----
  u16x8 Bf[8];
  const float* ibase = in + (size_t)b * DIMc * Tt + t0 + myt;
  #pragma unroll
  for (int kt = 0; kt < 8; ++kt) {
    float v[8];
    #pragma unroll
    for (int j = 0; j < 8; ++j) v[j] = ibase[(size_t)(kt * 32 + quad * 8 + j) * Tt];
    u16x8 pk;
    #pragma unroll
    for (int j = 0; j < 8; ++j) pk[j] = f2b(v[j]);
    Bf[kt] = pk;
  }
  // ---- rr2 of own token; cache rnd in regs for the q-update ----
  float rr2v = 0.f, rv[16];
  const float* rb = rnd + ((size_t)b * Tt + t0) * Dd;
  #pragma unroll
  for (int tt = 0; tt < 16; ++tt) {
    rv[tt] = rb[(size_t)(w * 16 + tt) * Dd + lane];
    float s = rv[tt] * rv[tt];
    s += __shfl_xor(s, 1);  s += __shfl_xor(s, 2);  s += __shfl_xor(s, 4);
    s += __shfl_xor(s, 8);  s += __shfl_xor(s, 16); s += __shfl_xor(s, 32);
    if (col == tt) rr2v = s;
  }
  __syncthreads();   // WinT DMA drained

  // ---- encode: X^T = WinT · In, acc init = bin (f32-exact bias) ----
  f32x4 acc[4];
  #pragma unroll
  for (int mt = 0; mt < 4; ++mt) {
    float4 bi = *(const float4*)(bin + mt * 16 + quad * 4);
    f32x4 a = {bi.x, bi.y, bi.z, bi.w};
    const int d = mt * 16 + col;
    #pragma unroll
    for (int kt = 0; kt < 8; ++kt) {
      u16x8 A = *(const u16x8*)(WinT + d * 256 + (((kt * 4 + quad) ^ (d & 7)) << 3));
      a = mfma16(A, Bf[kt], a);
    }
    acc[mt] = a;
  }
  float x2v = 0.f;
  #pragma unroll
  for (int mt = 0; mt < 4; ++mt) {
    #pragma unroll
    for (int r = 0; r < 4; ++r) x2v = fmaf(acc[mt][r], acc[mt][r], x2v);
    u32x2 px = { f2b2(acc[mt][0], acc[mt][1]), f2b2(acc[mt][2], acc[mt][3]) };
    const int bk  = mt * 2 + (quad >> 1);
    const int off = myt * 64 + ((bk ^ (myt & 7)) << 3) + (quad & 1) * 4;
    *(u32x2*)(Xt + off) = px;
  }
  x2v += __shfl_xor(x2v, 16);
  x2v += __shfl_xor(x2v, 32);
  __syncthreads();   // Xt complete; WinT dead -> WoX DMA can start

  // ---- WoX DMA (async; consumed after next barrier) ----
  #pragma unroll
  for (int ii = 0; ii < 8; ++ii) {
    const int i = w + 4 * ii;
    dma16(wsu + WOX_U + i * 512 + lane * 8, WoX + i * 512);
  }
  // ---- distances: wave-private 256-code slice; fragment-ready CbF from ws ----
  u16x8 Xa[4], Xb[4];
  #pragma unroll
  for (int nt = 0; nt < 4; ++nt) {
    const int tr = nt * 16 + col;
    Xa[nt] = *(const u16x8*)(Xt + tr * 64 + ((quad ^ (tr & 7)) << 3));
    Xb[nt] = *(const u16x8*)(Xt + tr * 64 + (((4 + quad) ^ (tr & 7)) << 3));
  }
  float minv[4];
  #pragma unroll
  for (int i = 0; i < 4; ++i) minv[i] = 3.4e38f;
  const u16* cwf   = wsu + CBF_U + (size_t)(w * 256) * 64;
  const float* cnp = (const float*)(wsu + CN_U) + w * 256;
  #pragma unroll 4
  for (int mi = 0; mi < 16; ++mi) {
    u16x8 A0 = *(const u16x8*)(cwf + (mi * 16 + col) * 64 + quad * 8);
    u16x8 A1 = *(const u16x8*)(cwf + (mi * 16 + col) * 64 + 32 + quad * 8);
    f32x4 cn4 = *(const f32x4*)(cnp + mi * 16 + quad * 4);
    #pragma unroll
    for (int nt = 0; nt < 4; ++nt) {
      f32x4 a = mfma16(A0, Xa[nt], cn4);    // c^2 + x·(-2c)
      a = mfma16(A1, Xb[nt], a);
      #pragma unroll
      for (int r = 0; r < 4; ++r) minv[nt] = fminf(minv[nt], a[r]);
    }
  }
  #pragma unroll
  for (int nt = 0; nt < 4; ++nt) {
    float m = minv[nt];
    m = fminf(m, __shfl_xor(m, 16));
    m = fminf(m, __shfl_xor(m, 32));
    mnp[w * 64 + nt * 16 + col] = m;        // all quads write same value
  }
  __syncthreads();   // mnp ready + WoX DMA drained

  // ---- q = x + sc*rnd (own token rows; lane = d; rnd from reg cache) ----
  float mv = 3.4e38f;
  #pragma unroll
  for (int j = 0; j < 4; ++j) mv = fminf(mv, mnp[j * 64 + myt]);
  float r2  = fmaxf(x2v + mv, 0.f);                 // ||x - hard||^2
  float scv = sqrtf(r2) / (sqrtf(rr2v) + 1e-12f);
  #pragma unroll
  for (int tt = 0; tt < 16; ++tt) {
    float s  = __shfl(scv, tt);
    const int tr  = w * 16 + tt;
    const int idx = tr * 64 + (((lane >> 3) ^ (tr & 7)) << 3) + (lane & 7);
    Xt[idx] = f2b(fmaf(s, rv[tt], b2f(Xt[idx])));
  }

  // ---- decode: out = WoX · q, acc init = bout (f32-exact bias) ----
  u16x8 Q0 = *(const u16x8*)(Xt + myt * 64 + ((quad ^ (myt & 7)) << 3));
  u16x8 Q1 = *(const u16x8*)(Xt + myt * 64 + (((4 + quad) ^ (myt & 7)) << 3));
  float* ob0 = out + (size_t)b * DIMc * Tt + t0 + myt;
  #pragma unroll
  for (int mt = 0; mt < 16; ++mt) {
    const int c = mt * 16 + col;
    const u16* ar = WoX + c * 64;
    u16x8 A0 = *(const u16x8*)(ar + ((quad ^ (c & 7)) << 3));
    u16x8 A1 = *(const u16x8*)(ar + (((4 + quad) ^ (c & 7)) << 3));
    float4 bo = *(const float4*)(bout + mt * 16 + quad * 4);
    f32x4 a = {bo.x, bo.y, bo.z, bo.w};
    a = mfma16(A0, Q0, a);
    a = mfma16(A1, Q1, a);
    float* ob = ob0 + (size_t)(mt * 16 + quad * 4) * Tt;
    #pragma unroll
    for (int r = 0; r < 4; ++r) ob[(size_t)r * Tt] = a[r];
  }
}

extern "C" void kernel_launch(void* const* d_in, const int* in_sizes, int n_in,
                              void* d_out, int out_size, void* d_ws, size_t ws_size,
                              hipStream_t stream) {
  const float *in = nullptr, *cbp = nullptr, *rnd = nullptr, *bin = nullptr, *bout = nullptr;
  const float* w16[2] = {nullptr, nullptr}; int nw = 0;
  for (int i = 0; i < n_in; ++i) {
    switch (in_sizes[i]) {
      case 8388608: in  = (const float*)d_in[i]; break;
      case 65536:   cbp = (const float*)d_in[i]; break;
      case 2097152: rnd = (const float*)d_in[i]; break;
      case 64:      bin = (const float*)d_in[i]; break;
      case 256:     bout= (const float*)d_in[i]; break;
      case 16384:   if (nw < 2) w16[nw++] = (const float*)d_in[i]; break;
      default: break;
    }
  }
  if (!in)   in  = (const float*)d_in[0];
  if (!cbp)  cbp = (const float*)d_in[1];
  if (nw < 2) { w16[0] = (const float*)d_in[2]; w16[1] = (const float*)d_in[4]; }
  if (!bin)  bin = (const float*)d_in[3];
  if (!bout) bout = (const float*)d_in[5];
  if (!rnd)  rnd = (const float*)d_in[6];

  u16* wsu = (u16*)d_ws;
  nsvq_prep<<<64, 256, 0, stream>>>(cbp, w16[0], w16[1], wsu);
  nsvq_main<<<512, 256, 0, stream>>>(in, rnd, bin, bout, wsu, (float*)d_out);
}

// Round 5
// 112.981 us; speedup vs baseline: 1.0764x; 1.0250x over previous
//
#include <hip/hip_runtime.h>
#include <hip/hip_bf16.h>

typedef __bf16 bf16x8 __attribute__((ext_vector_type(8)));
typedef unsigned short u16x8 __attribute__((ext_vector_type(8)));
typedef unsigned int u32x2 __attribute__((ext_vector_type(2)));
typedef float f32x4 __attribute__((ext_vector_type(4)));
typedef unsigned short u16;

constexpr int DIMc = 256, Tt = 2048, Dd = 64;

// ws layout (u16 units):
//   CbF[1024][64] @0       : bf16(-2*c), fragment-row order (code-major) = 128 KB
//   CN[1024] f32  @65536   : ||c||^2 (exact partial-sum tree)            =   4 KB
//   WinT image    @67584   : [64][256] bf16, XOR-swizzled LDS image      =  32 KB
//   WoX  image    @83968   : [256][64] bf16, XOR-swizzled LDS image      =  32 KB
#define CBF_U  0
#define CN_U   65536
#define WINT_U 67584
#define WOX_U  83968

__device__ __forceinline__ u16 f2b(float f) {   // RNE float->bf16 bits
  unsigned u = __float_as_uint(f);
  return (u16)((u + 0x7FFFu + ((u >> 16) & 1u)) >> 16);
}
__device__ __forceinline__ float b2f(u16 v) {
  return __uint_as_float(((unsigned)v) << 16);
}
__device__ __forceinline__ unsigned f2b2(float a, float b) {  // packed RNE pair (low=a)
  return (unsigned)f2b(a) | ((unsigned)f2b(b) << 16);
}
__device__ __forceinline__ f32x4 mfma16(u16x8 a, u16x8 b, f32x4 c) {
  return __builtin_amdgcn_mfma_f32_16x16x32_bf16(
      __builtin_bit_cast(bf16x8, a), __builtin_bit_cast(bf16x8, b), c, 0, 0, 0);
}
// async 16B/lane global->LDS DMA; LDS dst = uniform base + lane*16 (HW rule)
__device__ __forceinline__ void dma16(const u16* g, u16* l) {
  __builtin_amdgcn_global_load_lds(
      (const __attribute__((address_space(1))) unsigned int*)g,
      (__attribute__((address_space(3))) unsigned int*)l, 16, 0, 0);
}

// Prep: all fp32->bf16 weight conversion + transposition done ONCE (not per block).
__global__ void nsvq_prep(const float* __restrict__ cb, const float* __restrict__ Win,
                          const float* __restrict__ Wout, u16* __restrict__ wsu) {
  const int g = blockIdx.x * 256 + threadIdx.x;   // 64 blocks -> 16384 threads
  {  // CbF: 4 values/thread, value = bf16(-2c); row k is MFMA-A fragment-ready
    const int k = g >> 4, j = (g & 15) << 2;
    float4 v = *(const float4*)(cb + k * 64 + j);
    u16* row = wsu + CBF_U + k * 64 + j;
    row[0] = f2b(-2.f * v.x); row[1] = f2b(-2.f * v.y);
    row[2] = f2b(-2.f * v.z); row[3] = f2b(-2.f * v.w);
  }
  if (g < 1024) {  // CN: exact same partial-sum tree as the old in-kernel version
    const float* cr = cb + g * 64;
    float p[4];
    #pragma unroll
    for (int q = 0; q < 4; ++q) {
      float4 a0 = ((const float4*)(cr + q * 8))[0],      a1 = ((const float4*)(cr + q * 8))[1];
      float4 a2 = ((const float4*)(cr + 32 + q * 8))[0], a3 = ((const float4*)(cr + 32 + q * 8))[1];
      float pA = fmaf(a0.w, a0.w, fmaf(a0.z, a0.z, fmaf(a0.y, a0.y, a0.x * a0.x)));
      float pB = fmaf(a1.w, a1.w, fmaf(a1.z, a1.z, fmaf(a1.y, a1.y, a1.x * a1.x)));
      float pC = fmaf(a2.w, a2.w, fmaf(a2.z, a2.z, fmaf(a2.y, a2.y, a2.x * a2.x)));
      float pD = fmaf(a3.w, a3.w, fmaf(a3.z, a3.z, fmaf(a3.y, a3.y, a3.x * a3.x)));
      p[q] = (pA + pB) + (pC + pD);
    }
    ((float*)(wsu + CN_U))[g] = (p[0] + p[1]) + (p[2] + p[3]);
  }
  {  // WinT image: [d][c] swizzled (exact LDS image for DMA)
    const int d = g >> 8, c = g & 255;
    wsu[WINT_U + d * 256 + (((c >> 3) ^ (d & 7)) << 3) + (c & 7)] = f2b(Win[c * 64 + d]);
  }
  {  // WoX image: [c][d] swizzled (exact LDS image for DMA)
    const int c = g >> 6, d = g & 63;
    wsu[WOX_U + c * 64 + (((d >> 3) ^ (c & 7)) << 3) + (d & 7)] = f2b(Wout[d * 256 + c]);
  }
}

// Main: block = 64 tokens, 256 threads (4 waves), grid 512 (2 blocks/CU).
// LDS (u16): WinT[64][256] swz @0 ; WoX[256][64] swz @16384 ; Xt[64][64] swz
// @32768 ; mnp[4][64]f @36864. Total 74,752 B -> 2 blocks/CU. 3 barriers.
__global__ __launch_bounds__(256, 2) void nsvq_main(
    const float* __restrict__ in, const float* __restrict__ rnd,
    const float* __restrict__ bin, const float* __restrict__ bout,
    const u16* __restrict__ wsu, float* __restrict__ out) {
  __shared__ u16 sm[37376];
  u16* const WinT = sm;                     // [64][256] bf16 swz (encode A)
  u16* const WoX  = sm + 16384;             // [256][64] bf16 swz (decode A)
  u16* const Xt   = sm + 32768;             // [64][64] bf16 x (later q), swz
  float* const mnp = (float*)(sm + 36864);  // [4][64] per-wave code-slice mins

  const int tid  = threadIdx.x;
  const int lane = tid & 63;
  const int w    = tid >> 6;                // 0..3
  const int quad = lane >> 4, col = lane & 15;
  const int b    = blockIdx.x >> 5;         // 16 batches x 32 token-tiles
  const int t0   = (blockIdx.x & 31) << 6;
  const int myt  = w * 16 + col;            // own token row in block (0..63)

  // ---- WinT + WoX DMA (64 KB = 64 instrs, 16 per wave), fully async ----
  #pragma unroll
  for (int ii = 0; ii < 8; ++ii) {
    const int i = w + 4 * ii;
    dma16(wsu + WINT_U + i * 512 + lane * 8, WinT + i * 512);
  }
  #pragma unroll
  for (int ii = 0; ii < 8; ++ii) {
    const int i = w + 4 * ii;
    dma16(wsu + WOX_U + i * 512 + lane * 8, WoX + i * 512);
  }
  // ---- encode B-fragments straight from global (own token only; 64B-granule) ----
  u16x8 Bf[8];
  const float* ibase = in + (size_t)b * DIMc * Tt + t0 + myt;
  #pragma unroll
  for (int kt = 0; kt < 8; ++kt) {
    float v[8];
    #pragma unroll
    for (int j = 0; j < 8; ++j) v[j] = ibase[(size_t)(kt * 32 + quad * 8 + j) * Tt];
    u16x8 pk;
    #pragma unroll
    for (int j = 0; j < 8; ++j) pk[j] = f2b(v[j]);
    Bf[kt] = pk;
  }
  // ---- rnd in acc-fragment layout (token=col, d=mt*16+quad*4+r); rr2 reduce ----
  float4 rq[4];
  {
    const float* rbase = rnd + ((size_t)b * Tt + t0 + myt) * Dd + quad * 4;
    #pragma unroll
    for (int mt = 0; mt < 4; ++mt) rq[mt] = *(const float4*)(rbase + mt * 16);
  }
  float rr2v = 0.f;
  #pragma unroll
  for (int mt = 0; mt < 4; ++mt) {
    rr2v = fmaf(rq[mt].x, rq[mt].x, rr2v); rr2v = fmaf(rq[mt].y, rq[mt].y, rr2v);
    rr2v = fmaf(rq[mt].z, rq[mt].z, rr2v); rr2v = fmaf(rq[mt].w, rq[mt].w, rr2v);
  }
  rr2v += __shfl_xor(rr2v, 16);
  rr2v += __shfl_xor(rr2v, 32);             // full ||rnd||^2, replicated over quads
  __syncthreads();   // WinT + WoX DMA drained

  // ---- encode: X^T = WinT · In, acc init = bin (f32-exact bias) ----
  f32x4 acc[4];
  #pragma unroll
  for (int mt = 0; mt < 4; ++mt) {
    float4 bi = *(const float4*)(bin + mt * 16 + quad * 4);
    f32x4 a = {bi.x, bi.y, bi.z, bi.w};
    const int d = mt * 16 + col;
    #pragma unroll
    for (int kt = 0; kt < 8; ++kt) {
      u16x8 A = *(const u16x8*)(WinT + d * 256 + (((kt * 4 + quad) ^ (d & 7)) << 3));
      a = mfma16(A, Bf[kt], a);
    }
    acc[mt] = a;
  }
  float x2v = 0.f;
  #pragma unroll
  for (int mt = 0; mt < 4; ++mt) {
    #pragma unroll
    for (int r = 0; r < 4; ++r) x2v = fmaf(acc[mt][r], acc[mt][r], x2v);
    u32x2 px = { f2b2(acc[mt][0], acc[mt][1]), f2b2(acc[mt][2], acc[mt][3]) };
    const int bk  = mt * 2 + (quad >> 1);
    const int off = myt * 64 + ((bk ^ (myt & 7)) << 3) + (quad & 1) * 4;
    *(u32x2*)(Xt + off) = px;
  }
  x2v += __shfl_xor(x2v, 16);
  x2v += __shfl_xor(x2v, 32);
  __syncthreads();   // Xt(x) ready for cross-wave reads

  // ---- distances: wave-private 256-code slice; fragment-ready CbF from ws ----
  u16x8 Xa[4], Xb[4];
  #pragma unroll
  for (int nt = 0; nt < 4; ++nt) {
    const int tr = nt * 16 + col;
    Xa[nt] = *(const u16x8*)(Xt + tr * 64 + ((quad ^ (tr & 7)) << 3));
    Xb[nt] = *(const u16x8*)(Xt + tr * 64 + (((4 + quad) ^ (tr & 7)) << 3));
  }
  float minv[4];
  #pragma unroll
  for (int i = 0; i < 4; ++i) minv[i] = 3.4e38f;
  const u16* cwf   = wsu + CBF_U + (size_t)(w * 256) * 64;
  const float* cnp = (const float*)(wsu + CN_U) + w * 256;
  #pragma unroll 4
  for (int mi = 0; mi < 16; ++mi) {
    u16x8 A0 = *(const u16x8*)(cwf + (mi * 16 + col) * 64 + quad * 8);
    u16x8 A1 = *(const u16x8*)(cwf + (mi * 16 + col) * 64 + 32 + quad * 8);
    f32x4 cn4 = *(const f32x4*)(cnp + mi * 16 + quad * 4);
    #pragma unroll
    for (int nt = 0; nt < 4; ++nt) {
      f32x4 a = mfma16(A0, Xa[nt], cn4);    // c^2 + x·(-2c)
      a = mfma16(A1, Xb[nt], a);
      #pragma unroll
      for (int r = 0; r < 4; ++r) minv[nt] = fminf(minv[nt], a[r]);
    }
  }
  #pragma unroll
  for (int nt = 0; nt < 4; ++nt) {
    float m = minv[nt];
    m = fminf(m, __shfl_xor(m, 16));
    m = fminf(m, __shfl_xor(m, 32));
    mnp[w * 64 + nt * 16 + col] = m;        // all quads write same value
  }
  __syncthreads();   // mnp ready; all Xt(x) reads complete

  // ---- q = x + sc*rnd entirely in registers (acc layout); store q to Xt ----
  float mv = 3.4e38f;
  #pragma unroll
  for (int j = 0; j < 4; ++j) mv = fminf(mv, mnp[j * 64 + myt]);
  float r2  = fmaxf(x2v + mv, 0.f);                 // ||x - hard||^2
  float scv = sqrtf(r2) / (sqrtf(rr2v) + 1e-12f);   // own token's scale (per col)
  #pragma unroll
  for (int mt = 0; mt < 4; ++mt) {
    float q0 = fmaf(scv, rq[mt].x, acc[mt][0]);
    float q1 = fmaf(scv, rq[mt].y, acc[mt][1]);
    float q2 = fmaf(scv, rq[mt].z, acc[mt][2]);
    float q3 = fmaf(scv, rq[mt].w, acc[mt][3]);
    u32x2 pq = { f2b2(q0, q1), f2b2(q2, q3) };
    const int bk  = mt * 2 + (quad >> 1);
    const int off = myt * 64 + ((bk ^ (myt & 7)) << 3) + (quad & 1) * 4;
    *(u32x2*)(Xt + off) = pq;               // own row; same-wave LDS order suffices
  }

  // ---- decode: out = WoX · q, acc init = bout (f32-exact bias) ----
  u16x8 Q0 = *(const u16x8*)(Xt + myt * 64 + ((quad ^ (myt & 7)) << 3));
  u16x8 Q1 = *(const u16x8*)(Xt + myt * 64 + (((4 + quad) ^ (myt & 7)) << 3));
  float* ob0 = out + (size_t)b * DIMc * Tt + t0 + myt;
  #pragma unroll
  for (int mt = 0; mt < 16; ++mt) {
    const int c = mt * 16 + col;
    const u16* ar = WoX + c * 64;
    u16x8 A0 = *(const u16x8*)(ar + ((quad ^ (c & 7)) << 3));
    u16x8 A1 = *(const u16x8*)(ar + (((4 + quad) ^ (c & 7)) << 3));
    float4 bo = *(const float4*)(bout + mt * 16 + quad * 4);
    f32x4 a = {bo.x, bo.y, bo.z, bo.w};
    a = mfma16(A0, Q0, a);
    a = mfma16(A1, Q1, a);
    float* ob = ob0 + (size_t)(mt * 16 + quad * 4) * Tt;
    #pragma unroll
    for (int r = 0; r < 4; ++r) ob[(size_t)r * Tt] = a[r];
  }
}

extern "C" void kernel_launch(void* const* d_in, const int* in_sizes, int n_in,
                              void* d_out, int out_size, void* d_ws, size_t ws_size,
                              hipStream_t stream) {
  const float *in = nullptr, *cbp = nullptr, *rnd = nullptr, *bin = nullptr, *bout = nullptr;
  const float* w16[2] = {nullptr, nullptr}; int nw = 0;
  for (int i = 0; i < n_in; ++i) {
    switch (in_sizes[i]) {
      case 8388608: in  = (const float*)d_in[i]; break;
      case 65536:   cbp = (const float*)d_in[i]; break;
      case 2097152: rnd = (const float*)d_in[i]; break;
      case 64:      bin = (const float*)d_in[i]; break;
      case 256:     bout= (const float*)d_in[i]; break;
      case 16384:   if (nw < 2) w16[nw++] = (const float*)d_in[i]; break;
      default: break;
    }
  }
  if (!in)   in  = (const float*)d_in[0];
  if (!cbp)  cbp = (const float*)d_in[1];
  if (nw < 2) { w16[0] = (const float*)d_in[2]; w16[1] = (const float*)d_in[4]; }
  if (!bin)  bin = (const float*)d_in[3];
  if (!bout) bout = (const float*)d_in[5];
  if (!rnd)  rnd = (const float*)d_in[6];

  u16* wsu = (u16*)d_ws;
  nsvq_prep<<<64, 256, 0, stream>>>(cbp, w16[0], w16[1], wsu);
  nsvq_main<<<512, 256, 0, stream>>>(in, rnd, bin, bout, wsu, (float*)d_out);
}